// Round 9
// baseline (147.525 us; speedup 1.0000x reference)
//
#include <hip/hip_runtime.h>

typedef unsigned short u16;
typedef unsigned int u32;
using frag8 = __attribute__((ext_vector_type(8))) short;  // 8 bf16 (4 VGPRs)
using f32x4 = __attribute__((ext_vector_type(4))) float;
using u32x4 = __attribute__((ext_vector_type(4))) u32;

#define MFMA(a, b, c) __builtin_amdgcn_mfma_f32_16x16x32_bf16(a, b, c, 0, 0, 0)
#define SC 0.42466090014400953f  // 64^-0.25 * sqrt(log2 e)

// fp32 -> bf16 RNE, result in HIGH 16 bits (for v_perm packing)
__device__ __forceinline__ u32 bfh(float f) {
  u32 t = __float_as_uint(f);
  return t + 0x7fffu + ((t >> 16) & 1u);
}
// pack two fp32 -> u32 of 2 bf16, memory order [lo, hi]
__device__ __forceinline__ u32 pk2(float lo, float hi) {
  return __builtin_amdgcn_perm(bfh(hi), bfh(lo), 0x07060302u);
}

// ---------------------------------------------------------------------------
// R9: FULLY FUSED single kernel. The prepass + workspace round-trip
// (qkv -> ws 25MB -> flash) cost ~35-40us/iter (prepass kernel + extra
// launch + HBM handoff). Each block now converts its own K/V/Q tiles from
// raw fp32 qkv on the fly (redundant across the 16 q-tile blocks of a head,
// but reads come from L2/L3: ~512MB @ ~11TB/s aggregate, within budget).
//
// block = 512 threads = 8 waves = 4 t-groups (32 t) x 2 s-halves (1024 s).
// Grid 512 (XCD-swizzled). 32-s K/V tiles, 32 steps.
// Staging (reg-staged, replaces global_load_lds since fp32->bf16 convert +
// transpose/sigma-permute happen in-flight):
//  K: thread (s=inner&31, o=inner>>5) reads K column [c=o*8..+7][s] as 8
//     dword loads (coalesced along s across the wave), converts+scales,
//     writes ONE ds_write_b128 at [s][slot (o^(s&7))] -- IDENTICAL LDS image
//     to the old pre-swizzled global_load_lds staging of Kt.
//  V: thread (c=inner>>2, iv=inner&3) reads s_local [4iv..+3] and [16+4iv..+3]
//     (2 dense float4), which form exactly stored sigma-octet p=8iv..8iv+7
//     (sigma: p -> s = 16*(e>>2) + 4w + (e&3), run-of-4 preserving), writes
//     ONE ds_write_b128 at [c][slot (iv ^ ((c>>1)&3))] -- identical to Vn.
//  Q: prologue-only, 32 scattered dword loads/lane (wave-coalesced along t),
//     scale+convert -> aQ frags identical to Qt reads.
// Sync: ONE raw barrier per step: s_waitcnt lgkmcnt(0) + s_barrier (NO vmcnt
// drain -- tile n+2's global loads stay in flight across it; compiler emits
// counted vmcnt before the register uses). 2 LDS buffers: body n writes tile
// n+1 into buf (n+1)%2 whose old tile n-1 was last read one barrier earlier.
// LDS (u16): buf0 [0,8192) buf1 [8192,16384); per buf: K h0 [0,2048)
//   K h1 [2048,4096) V h0 [4096,6144) V h1 [6144,8192).
//   Epilogue O/l exchange reuses [0, 36864B) after the final barrier.
// ---------------------------------------------------------------------------

#define ISSUE(N)                                                            \
  {                                                                         \
    _Pragma("unroll") for (int e = 0; e < 8; ++e)                           \
        kr[e] = Kb[(size_t)e * 2048 + (N) * 32];                            \
    vr0 = *(const float4*)(Vb + (N) * 32);                                  \
    vr1 = *(const float4*)(Vb + (N) * 32 + 16);                             \
  }

#define WRT(BUF)                                                            \
  {                                                                         \
    u32 kp0 = pk2(kr[0] * SC, kr[1] * SC), kp1 = pk2(kr[2] * SC, kr[3] * SC), \
        kp2 = pk2(kr[4] * SC, kr[5] * SC), kp3 = pk2(kr[6] * SC, kr[7] * SC); \
    *(uint4*)(ldsbase + (BUF) + kDo) = make_uint4(kp0, kp1, kp2, kp3);      \
    u32 vp0 = pk2(vr0.x, vr0.y), vp1 = pk2(vr0.z, vr0.w),                   \
        vp2 = pk2(vr1.x, vr1.y), vp3 = pk2(vr1.z, vr1.w);                   \
    *(uint4*)(ldsbase + (BUF) + vDo) = make_uint4(vp0, vp1, vp2, vp3);      \
  }

// body: frag-read tile n from CUR -> S MFMA -> write tile n+1 (regs->bf16->
// LDS CUR^1) -> issue tile n+2 loads -> exp/pack -> PV MFMA -> raw barrier
#define BODY(CUR, DOWR, DOISS, NISS)                                        \
  {                                                                         \
    frag8 kf0[2], kf1[2];                                                   \
    _Pragma("unroll") for (int i = 0; i < 2; ++i) {                         \
      kf0[i] = *(const frag8*)(ldsbase + (CUR) + kAo + i * 1024);           \
      kf1[i] = *(const frag8*)(ldsbase + (CUR) + kBo + i * 1024);           \
    }                                                                       \
    f32x4 S[2][2];                                                          \
    __builtin_amdgcn_s_setprio(1);                                          \
    _Pragma("unroll") for (int j = 0; j < 2; ++j) {                         \
      _Pragma("unroll") for (int i = 0; i < 2; ++i) {                       \
        f32x4 z = {0.f, 0.f, 0.f, 0.f};                                     \
        z = MFMA(kf0[i], aQ0[j], z);                                        \
        z = MFMA(kf1[i], aQ1[j], z);                                        \
        S[i][j] = z;                                                        \
      }                                                                     \
    }                                                                       \
    __builtin_amdgcn_s_setprio(0);                                          \
    if (DOWR) {                                                             \
      WRT((CUR) ^ 8192)                                                     \
    }                                                                       \
    if (DOISS) {                                                            \
      ISSUE(NISS)                                                           \
    }                                                                       \
    frag8 vf[4];                                                            \
    _Pragma("unroll") for (int i = 0; i < 4; ++i)                           \
        vf[i] = *(const frag8*)(ldsbase + (CUR) + vAo + i * 512);           \
    _Pragma("unroll") for (int j = 0; j < 2; ++j) {                         \
      u32 pw[4];                                                            \
      _Pragma("unroll") for (int i = 0; i < 2; ++i) {                       \
        float p0 = __builtin_amdgcn_exp2f(S[i][j][0]);                      \
        float p1 = __builtin_amdgcn_exp2f(S[i][j][1]);                      \
        float p2 = __builtin_amdgcn_exp2f(S[i][j][2]);                      \
        float p3 = __builtin_amdgcn_exp2f(S[i][j][3]);                      \
        u32 a0 = __float_as_uint(p0) + 0x8000u;                             \
        u32 a1 = __float_as_uint(p1) + 0x8000u;                             \
        u32 a2 = __float_as_uint(p2) + 0x8000u;                             \
        u32 a3 = __float_as_uint(p3) + 0x8000u;                             \
        pw[i * 2] = __builtin_amdgcn_perm(a1, a0, 0x07060302u);             \
        pw[i * 2 + 1] = __builtin_amdgcn_perm(a3, a2, 0x07060302u);         \
      }                                                                     \
      u32x4 va = {pw[0], pw[1], pw[2], pw[3]};                              \
      frag8 pf = __builtin_bit_cast(frag8, va);                             \
      __builtin_amdgcn_s_setprio(1);                                        \
      _Pragma("unroll") for (int i = 0; i < 4; ++i)                         \
          o[i][j] = MFMA(vf[i], pf, o[i][j]);                               \
      lacc[j] = MFMA(ones, pf, lacc[j]);                                    \
      __builtin_amdgcn_s_setprio(0);                                        \
    }                                                                       \
    asm volatile("s_waitcnt lgkmcnt(0)" ::: "memory");                      \
    __builtin_amdgcn_s_barrier();                                           \
    __builtin_amdgcn_sched_barrier(0);                                      \
  }

__global__ __launch_bounds__(512, 4) void attn_fused_kernel(
    const float* __restrict__ qkv, float* __restrict__ out) {
  __shared__ __align__(16) unsigned char smem[36864];
  u16* ldsbase = (u16*)smem;

  // XCD swizzle: blk&7 = XCD; 4 heads per XCD
  const int blk = blockIdx.x;
  const int ii = blk >> 3;
  const int b = ((blk & 7) << 2) + (ii >> 4);  // head 0..31
  const int qt = ii & 15;                      // q-tile (128 t each)

  const int tid = threadIdx.x;  // 0..511
  const int w = tid >> 6;
  const int tg = w & 3;   // t-group: t in [32*tg, 32*tg+32) of the q-tile
  const int sh = w >> 2;  // s-half: s in [1024*sh, 1024*sh+1024)
  const int lane = tid & 63;
  const int s16 = lane & 15, q = lane >> 4;
  const int x = s16 & 7;
  const int x2 = (s16 >> 1) & 3;

  const int basec = (b >> 3) * 1536 + (b & 7) * 192;
  const float* Qraw = qkv + (size_t)basec * 2048;
  const float* Kraw = qkv + (size_t)(basec + 64) * 2048;
  const float* Vraw = qkv + (size_t)(basec + 128) * 2048;

  // staging thread mapping (256 threads per s-half)
  const int inner = tid & 255;
  const int half = tid >> 8;
  const int sk = inner & 31, ok = inner >> 5;  // K: dest row s, c-octet
  const int cv = inner >> 2, iv = inner & 3;   // V: dest row c, s-octet
  const float* Kb = Kraw + (size_t)(ok * 8) * 2048 + half * 1024 + sk;
  const float* Vb = Vraw + (size_t)cv * 2048 + half * 1024 + iv * 4;
  // LDS write offsets (u16, within a buffer)
  const int kDo = half * 2048 + sk * 64 + ((ok ^ (sk & 7)) * 8);
  const int vDo = 4096 + half * 2048 + cv * 32 + ((iv ^ ((cv >> 1) & 3)) * 8);

  // fragment read offsets within a buffer (XOR-swizzled, same as R7)
  const int kAo = sh * 2048 + s16 * 64 + ((q ^ x) * 8);
  const int kBo = sh * 2048 + s16 * 64 + (((q + 4) ^ x) * 8);
  const int vAo = 4096 + sh * 2048 + s16 * 32 + ((q ^ x2) * 8);

  float kr[8];
  float4 vr0, vr1;

  // prologue: issue tile 0; build Q frags from raw fp32 (scale+RNE convert)
  ISSUE(0)
  frag8 aQ0[2], aQ1[2];
#pragma unroll
  for (int j = 0; j < 2; ++j) {
    const float* qr = Qraw + (size_t)(qt * 128 + tg * 32 + j * 16 + s16);
    float qa[8], qb[8];
#pragma unroll
    for (int e = 0; e < 8; ++e) {
      qa[e] = qr[(size_t)(q * 8 + e) * 2048];
      qb[e] = qr[(size_t)((q + 4) * 8 + e) * 2048];
    }
    u32 w0 = pk2(qa[0] * SC, qa[1] * SC), w1 = pk2(qa[2] * SC, qa[3] * SC),
        w2 = pk2(qa[4] * SC, qa[5] * SC), w3 = pk2(qa[6] * SC, qa[7] * SC);
    u32x4 va = {w0, w1, w2, w3};
    aQ0[j] = __builtin_bit_cast(frag8, va);
    u32 y0 = pk2(qb[0] * SC, qb[1] * SC), y1 = pk2(qb[2] * SC, qb[3] * SC),
        y2 = pk2(qb[4] * SC, qb[5] * SC), y3 = pk2(qb[6] * SC, qb[7] * SC);
    u32x4 vb4 = {y0, y1, y2, y3};
    aQ1[j] = __builtin_bit_cast(frag8, vb4);
  }
  WRT(0)    // tile 0 -> buf0 (compiler inserts the vmcnt wait on kr/vr)
  ISSUE(1)  // tile 1 loads in flight across the barrier
  asm volatile("s_waitcnt lgkmcnt(0)" ::: "memory");
  __builtin_amdgcn_s_barrier();
  __builtin_amdgcn_sched_barrier(0);

  // ones A-fragment (bf16 1.0) for the row-sum MFMA
  frag8 ones;
#pragma unroll
  for (int z = 0; z < 8; ++z) ones[z] = (short)0x3F80;

  f32x4 o[4][2];
#pragma unroll
  for (int i = 0; i < 4; ++i)
#pragma unroll
    for (int j = 0; j < 2; ++j) o[i][j] = (f32x4){0.f, 0.f, 0.f, 0.f};
  f32x4 lacc[2];
#pragma unroll
  for (int j = 0; j < 2; ++j) lacc[j] = (f32x4){0.f, 0.f, 0.f, 0.f};

  for (int m = 0; m < 15; ++m) {
    BODY(0, 1, 1, 2 * m + 2)
    BODY(8192, 1, 1, 2 * m + 3)
  }
  BODY(0, 1, 0, 0)     // tile 30; writes tile 31 -> buf1
  BODY(8192, 0, 0, 0)  // tile 31; nothing left to stage

  // per-wave denominators from the ones-MFMA (all acc rows identical)
  float lp[2];
#pragma unroll
  for (int j = 0; j < 2; ++j) lp[j] = lacc[j][0];

  // combine s-halves through LDS (bufs dead after final body barrier)
  // per lane: 8 f32x4 (o) + 2 floats (lp), stride 36 floats (144 B)
  float* fb = (float*)ldsbase;
  if (sh == 1) {
    float* ow = fb + tg * 2304 + lane * 36;
#pragma unroll
    for (int i = 0; i < 4; ++i)
#pragma unroll
      for (int j = 0; j < 2; ++j) *(f32x4*)(ow + (i * 2 + j) * 4) = o[i][j];
    ow[32] = lp[0];
    ow[33] = lp[1];
  }
  __syncthreads();
  if (sh == 0) {
    const float* ow = fb + tg * 2304 + lane * 36;
    float rl[2];
#pragma unroll
    for (int j = 0; j < 2; ++j) rl[j] = 1.0f / (lp[j] + ow[32 + j]);
    // lane stores O^T[c = i*16+q*4+r][t = qt*128 + tg*32 + 16j + s16]
    float* ob =
        out + (size_t)(b * 64 + q * 4) * 2048 + qt * 128 + tg * 32 + s16;
#pragma unroll
    for (int i = 0; i < 4; ++i)
#pragma unroll
      for (int j = 0; j < 2; ++j) {
        f32x4 oo = *(const f32x4*)(ow + (i * 2 + j) * 4);
#pragma unroll
        for (int r = 0; r < 4; ++r)
          ob[(size_t)(i * 16 + r) * 2048 + j * 16] =
              (o[i][j][r] + oo[r]) * rl[j];
      }
  }
}

extern "C" void kernel_launch(void* const* d_in, const int* in_sizes, int n_in,
                              void* d_out, int out_size, void* d_ws,
                              size_t ws_size, hipStream_t stream) {
  const float* qkv = (const float*)d_in[0];
  float* out = (float*)d_out;
  (void)d_ws;
  (void)ws_size;
  attn_fused_kernel<<<512, 512, 0, stream>>>(qkv, out);
}